// Round 1
// baseline (1895.911 us; speedup 1.0000x reference)
//
#include <hip/hip_runtime.h>
#include <cstddef>

#define B_ 256
#define T_ 128
#define F_ 256
#define H_ 512
#define C_ 10

#define TEAMS 32     // teams; team owns BS batch rows (2 blocks co-resident/CU)
#define TB    16     // blocks per team; member owns NS output columns
#define BS    8      // batch rows per team (two interleaved groups of BSH)
#define BSH   4      // batch rows per group (A = rows 0..3, B = rows 4..7)
#define NS    32     // n columns per member block

// ---------------------------------------------------------------------------
// GEMM: Cout[M, 512] = A[M, K] @ W[512, K]^T + b1 + b2   (fp32, vector ALU)
// BM=BN=128, BK=16, 256 threads, 8x8 micro-tile (FMA:ds_read = 16:1).
// Sync-free beyond __syncthreads; cannot hang.  (unchanged)
// ---------------------------------------------------------------------------
template<int K>
__global__ __launch_bounds__(256, 2) void gemm_bias_kernel(
    const float* __restrict__ A, const float* __restrict__ W,
    const float* __restrict__ b1, const float* __restrict__ b2,
    float* __restrict__ Cout)
{
    __shared__ alignas(16) float As[16][132];
    __shared__ alignas(16) float Ws[16][132];

    const int tid = threadIdx.x;
    const int m0 = blockIdx.x * 128;
    const int n0 = blockIdx.y * 128;
    const int tx = tid & 15;        // n dim: 16 threads * 8
    const int ty = tid >> 4;        // m dim: 16 threads * 8

    float acc[8][8];
#pragma unroll
    for (int i = 0; i < 8; i++)
#pragma unroll
        for (int j = 0; j < 8; j++) acc[i][j] = 0.f;

    for (int k0 = 0; k0 < K; k0 += 16) {
        // A tile: 128 rows x 16 k = 512 float4, 2/thread, coalesced along k
#pragma unroll
        for (int i = 0; i < 2; i++) {
            int f = tid + 256 * i;
            int m = f >> 2, k4 = (f & 3) * 4;
            float4 v = *(const float4*)(A + (size_t)(m0 + m) * K + k0 + k4);
            As[k4 + 0][m] = v.x; As[k4 + 1][m] = v.y;
            As[k4 + 2][m] = v.z; As[k4 + 3][m] = v.w;
        }
        // W tile: 128 rows x 16 k = 512 float4, 2/thread
#pragma unroll
        for (int i = 0; i < 2; i++) {
            int f = tid + 256 * i;
            int n = f >> 2, k4 = (f & 3) * 4;
            float4 v = *(const float4*)(W + (size_t)(n0 + n) * K + k0 + k4);
            Ws[k4 + 0][n] = v.x; Ws[k4 + 1][n] = v.y;
            Ws[k4 + 2][n] = v.z; Ws[k4 + 3][n] = v.w;
        }
        __syncthreads();

#pragma unroll
        for (int kk = 0; kk < 16; kk++) {
            float4 a0 = *(const float4*)&As[kk][ty * 8];
            float4 a1 = *(const float4*)&As[kk][ty * 8 + 4];
            float4 w0 = *(const float4*)&Ws[kk][tx * 8];
            float4 w1 = *(const float4*)&Ws[kk][tx * 8 + 4];
            float a[8] = {a0.x, a0.y, a0.z, a0.w, a1.x, a1.y, a1.z, a1.w};
            float w[8] = {w0.x, w0.y, w0.z, w0.w, w1.x, w1.y, w1.z, w1.w};
#pragma unroll
            for (int i = 0; i < 8; i++)
#pragma unroll
                for (int j = 0; j < 8; j++)
                    acc[i][j] = fmaf(a[i], w[j], acc[i][j]);
        }
        __syncthreads();
    }

    float bias[8];
#pragma unroll
    for (int j = 0; j < 8; j++) {
        int n = n0 + tx * 8 + j;
        bias[j] = b1[n] + b2[n];
    }
#pragma unroll
    for (int i = 0; i < 8; i++) {
        int m = m0 + ty * 8 + i;
        float4 v0 = {acc[i][0] + bias[0], acc[i][1] + bias[1],
                     acc[i][2] + bias[2], acc[i][3] + bias[3]};
        float4 v1 = {acc[i][4] + bias[4], acc[i][5] + bias[5],
                     acc[i][6] + bias[6], acc[i][7] + bias[7]};
        *(float4*)(Cout + (size_t)m * H_ + n0 + tx * 8)     = v0;
        *(float4*)(Cout + (size_t)m * H_ + n0 + tx * 8 + 4) = v1;
    }
}

// ---------------------------------------------------------------------------
// Team-parallel recurrent scan, fp32, W_hh register-stationary.
//
// Transport (verified r4/r5/r7): h moves via RELAXED agent-scope atomics on
// `data`; __syncthreads() drains vmcnt(0) before lane 0 signals, so h-stores
// are globally visible before the signal. Barrier: r5/r7-PROVEN monotonic
// fetch_add counter (flag+ballot banned — hung in r6 AND r8).
//
// Round-10 change (barrier-latency hiding): the team's BS=8 rows are split
// into two INDEPENDENT groups A (rows 0..3) and B (rows 4..7), each with its
// own monotonic counter on its own 64B line. Per time-step: compute A,
// signal A, compute B (A's barrier resolves meanwhile), signal B. The spin
// for group X's step t-1 executes one full opposite-phase (~stage+FMA+reduce,
// ~1.7k cyc) after X's signal, hiding the ~signal-serialize+detect+skew
// latency that previously sat exposed on the critical path every step.
// Primitives, counters' monotonic gen0 continuation, and per-output FMA
// order are unchanged (bit-identical numerics).
// ---------------------------------------------------------------------------
__global__ __launch_bounds__(256, 2) void scan_team_kernel(
    float* __restrict__ data, const float* __restrict__ Whh,
    unsigned int* __restrict__ bar, int gen0)
{
    __shared__ alignas(16) float hsA[BSH][H_];        // 8 KB
    __shared__ alignas(16) float hsB[BSH][H_];        // 8 KB
    __shared__ alignas(16) float red[16][BSH][NS];    // 8 KB (reused A/B)

    const int tid  = threadIdx.x;
    const int team = blockIdx.x & 31;   // members congruent mod 32 -> same XCD
    const int mem  = blockIdx.x >> 5;   // 0..15
    const int b0   = team * BS;
    const int n0   = mem * NS;
    const int nl2  = tid & 15;          // col-pair index: cols n0+2*nl2, +1
    const int kg   = tid >> 4;          // 0..15, k-slice of 32
    const int n    = n0 + nl2 * 2;
    (void)mem;

    unsigned int* cntA = bar + team * 32;   // 128 B per team: two 64B lines
    unsigned int* cntB = cntA + 16;

    // ---- W slices (2 rows x 32 k) -> 16 float4, atomic-pinned (r7) ----
    float4 w0[8], w1[8];
    {
        const unsigned long long* q0 =
            (const unsigned long long*)(Whh + (size_t)n * H_ + (size_t)kg * 32);
        const unsigned long long* q1 =
            (const unsigned long long*)(Whh + (size_t)(n + 1) * H_ + (size_t)kg * 32);
#pragma unroll
        for (int j = 0; j < 8; j++) {
            union { unsigned long long q[2]; float4 f; } u;
            u.q[0] = __hip_atomic_load(q0 + 2 * j,     __ATOMIC_RELAXED,
                                       __HIP_MEMORY_SCOPE_AGENT);
            u.q[1] = __hip_atomic_load(q0 + 2 * j + 1, __ATOMIC_RELAXED,
                                       __HIP_MEMORY_SCOPE_AGENT);
            w0[j] = u.f;
            u.q[0] = __hip_atomic_load(q1 + 2 * j,     __ATOMIC_RELAXED,
                                       __HIP_MEMORY_SCOPE_AGENT);
            u.q[1] = __hip_atomic_load(q1 + 2 * j + 1, __ATOMIC_RELAXED,
                                       __HIP_MEMORY_SCOPE_AGENT);
            w1[j] = u.f;
        }
    }

    // Per-phase output: 4 rows x 32 cols = 128 outputs -> threads 0..127.
    const int orow = tid >> 5;          // 0..3 valid when tid < 128
    const int ocol = tid & 31;
    float* pA = data + ((size_t)(b0 + orow) * T_) * H_ + n0 + ocol;
    float* pB = data + ((size_t)(b0 + BSH + orow) * T_) * H_ + n0 + ocol;
    float projA = 0.f, projB = 0.f;
    if (tid < 128) { projA = *pA; projB = *pB; }   // t=0 prefetch (owner lines)

    // One phase: spin(own t-1) -> stage -> partial dots -> LDS reduce ->
    // epilogue store -> drain -> signal -> prefetch next proj.
#define PHASE(hsX, cntX, pX, projX, rowoff)                                    \
    {                                                                          \
        if (tid == 0) {                                                        \
            const unsigned target = (unsigned)TB * (unsigned)(gen0 + t);       \
            while (__hip_atomic_load(cntX, __ATOMIC_RELAXED,                   \
                                     __HIP_MEMORY_SCOPE_AGENT) < target) {     \
                __builtin_amdgcn_s_sleep(2);                                   \
            }                                                                  \
        }                                                                      \
        __syncthreads();  /* release: group step t-1 visible */                \
        if (t == 0) {                                                          \
            _Pragma("unroll")                                                  \
            for (int i = 0; i < 2; i++)                                        \
                ((float4*)hsX)[tid + 256 * i] = float4{0.f, 0.f, 0.f, 0.f};    \
        } else {                                                               \
            const float* sp =                                                  \
                data + ((size_t)(b0 + rowoff) * T_ + (t - 1)) * H_;            \
            _Pragma("unroll")                                                  \
            for (int b = 0; b < BSH; b++) {                                    \
                unsigned long long v = __hip_atomic_load(                      \
                    (const unsigned long long*)(sp + (size_t)b * T_ * H_) +    \
                        tid,                                                   \
                    __ATOMIC_RELAXED, __HIP_MEMORY_SCOPE_AGENT);               \
                *((unsigned long long*)&hsX[b][0] + tid) = v;                  \
            }                                                                  \
        }                                                                      \
        __syncthreads();                                                       \
        float p0[BSH], p1[BSH];                                                \
        _Pragma("unroll")                                                      \
        for (int b = 0; b < BSH; b++) { p0[b] = 0.f; p1[b] = 0.f; }            \
        _Pragma("unroll")                                                      \
        for (int j = 0; j < 8; j++) {                                          \
            const float4 wa = w0[j];                                           \
            const float4 wb = w1[j];                                           \
            const int kb = kg * 32 + j * 4;                                    \
            _Pragma("unroll")                                                  \
            for (int b = 0; b < BSH; b++) {                                    \
                float4 hv = *(const float4*)&hsX[b][kb];                       \
                p0[b] = fmaf(wa.x, hv.x, fmaf(wa.y, hv.y,                      \
                        fmaf(wa.z, hv.z, fmaf(wa.w, hv.w, p0[b]))));           \
                p1[b] = fmaf(wb.x, hv.x, fmaf(wb.y, hv.y,                      \
                        fmaf(wb.z, hv.z, fmaf(wb.w, hv.w, p1[b]))));           \
            }                                                                  \
        }                                                                      \
        _Pragma("unroll")                                                      \
        for (int b = 0; b < BSH; b++)                                          \
            *(float2*)&red[kg][b][nl2 * 2] = float2{p0[b], p1[b]};             \
        __syncthreads();                                                       \
        if (tid < 128) {                                                       \
            float s = 0.f;                                                     \
            _Pragma("unroll")                                                  \
            for (int g = 0; g < 16; g++) s += red[g][orow][ocol];              \
            float h = fmaxf(s + projX, 0.f);                                   \
            __hip_atomic_store(pX, h, __ATOMIC_RELAXED,                        \
                               __HIP_MEMORY_SCOPE_AGENT);                      \
        }                                                                      \
        __syncthreads();  /* drains vmcnt(0): h-stores visible pre-signal */   \
        if (tid == 0 && t < T_ - 1)                                            \
            __hip_atomic_fetch_add(cntX, 1u, __ATOMIC_RELAXED,                 \
                                   __HIP_MEMORY_SCOPE_AGENT);                  \
        if (tid < 128 && t < T_ - 1) { pX += H_; projX = *pX; }                \
    }

    for (int t = 0; t < T_; t++) {
        // A phase: spin for A(t-1) resolved during previous B phase
        PHASE(hsA, cntA, pA, projA, 0)
        // B phase: spin for B(t-1) resolved during the A phase above
        PHASE(hsB, cntB, pB, projB, BSH)
    }
#undef PHASE
}

// ---------------------------------------------------------------------------
// FC head: out[b][c] = sum_i h1[b][i] * Wfc[c][i] + bfc[c]   (unchanged)
// ---------------------------------------------------------------------------
__global__ __launch_bounds__(256) void fc_kernel(
    const float* __restrict__ Hl, const float* __restrict__ Wfc,
    const float* __restrict__ bfc, float* __restrict__ out)
{
    const int b = blockIdx.x;
    const int tid = threadIdx.x;
    const float* hb = Hl + (size_t)b * (T_ * H_);

    float acc[C_];
#pragma unroll
    for (int c = 0; c < C_; c++) acc[c] = 0.f;

    for (int i = tid * 4; i < T_ * H_; i += 256 * 4) {
        float4 hv = *(const float4*)(hb + i);
#pragma unroll
        for (int c = 0; c < C_; c++) {
            float4 wv = *(const float4*)(Wfc + (size_t)c * (T_ * H_) + i);
            acc[c] = fmaf(hv.x, wv.x, fmaf(hv.y, wv.y,
                     fmaf(hv.z, wv.z, fmaf(hv.w, wv.w, acc[c]))));
        }
    }

    __shared__ float red[4][C_];
#pragma unroll
    for (int c = 0; c < C_; c++) {
        float v = acc[c];
#pragma unroll
        for (int off = 32; off >= 1; off >>= 1) v += __shfl_xor(v, off, 64);
        if ((tid & 63) == 0) red[tid >> 6][c] = v;
    }
    __syncthreads();
    if (tid < C_) {
        float v = red[0][tid] + red[1][tid] + red[2][tid] + red[3][tid] + bfc[tid];
        out[(size_t)b * C_ + tid] = v;
    }
}

// ---------------------------------------------------------------------------
// Pipeline: proj0 GEMM -> scan0 -> proj1 GEMM -> scan1 -> FC.
// Team counters: 32 teams x TWO 64 B lines (A and B groups) in the first
// 4 KB of d_out (zeroed by hipMemsetAsync — graph-safe; fc_kernel fully
// overwrites d_out at the end; out_size = 10240 B >= 4 KB).
// Monotonic counters shared across both scans: each group signals steps
// 0..T-2 per scan (ends at TB*127), scan1 uses gen0=127 to continue.
// ---------------------------------------------------------------------------
extern "C" void kernel_launch(void* const* d_in, const int* in_sizes, int n_in,
                              void* d_out, int out_size, void* d_ws, size_t ws_size,
                              hipStream_t stream)
{
    (void)in_sizes; (void)n_in; (void)out_size; (void)ws_size;

    const float* x    = (const float*)d_in[0];
    const float* Wih0 = (const float*)d_in[1];
    const float* Whh0 = (const float*)d_in[2];
    const float* bih0 = (const float*)d_in[3];
    const float* bhh0 = (const float*)d_in[4];
    const float* Wih1 = (const float*)d_in[5];
    const float* Whh1 = (const float*)d_in[6];
    const float* bih1 = (const float*)d_in[7];
    const float* bhh1 = (const float*)d_in[8];
    const float* Wfc  = (const float*)d_in[9];
    const float* bfc  = (const float*)d_in[10];
    float* out = (float*)d_out;

    float* ws0 = (float*)d_ws;                    // [B][T][H] proj0 -> h0
    float* ws1 = ws0 + (size_t)B_ * T_ * H_;      // [B][T][H] proj1 -> h1
    unsigned int* bar = (unsigned int*)d_out;     // TEAMS x 2 x 16-dword lines

    hipMemsetAsync(bar, 0, TEAMS * 32 * sizeof(unsigned int), stream);

    dim3 gproj(B_ * T_ / 128, H_ / 128);   // (256, 4)

    gemm_bias_kernel<F_><<<gproj, 256, 0, stream>>>(x, Wih0, bih0, bhh0, ws0);
    scan_team_kernel<<<TEAMS * TB, 256, 0, stream>>>(ws0, Whh0, bar, 0);

    gemm_bias_kernel<H_><<<gproj, 256, 0, stream>>>(ws0, Wih1, bih1, bhh1, ws1);
    scan_team_kernel<<<TEAMS * TB, 256, 0, stream>>>(ws1, Whh1, bar, T_ - 1);

    fc_kernel<<<B_, 256, 0, stream>>>(ws1, Wfc, bfc, out);
}

// Round 2
// 1452.213 us; speedup vs baseline: 1.3055x; 1.3055x over previous
//
#include <hip/hip_runtime.h>
#include <cstddef>

#define B_ 256
#define T_ 128
#define F_ 256
#define H_ 512
#define C_ 10

#define TEAMS 32     // teams; team owns BS batch rows (2 blocks co-resident/CU)
#define TB    16     // blocks per team; member owns NS output columns
#define BS    8      // batch rows per team
#define NS    32     // n columns per member block

typedef short bf16x8 __attribute__((ext_vector_type(8)));
typedef float f32x4  __attribute__((ext_vector_type(4)));

// round-to-nearest-even fp32 -> bf16
__device__ __forceinline__ unsigned short f2bf_rn(float f) {
    unsigned u = __builtin_bit_cast(unsigned, f);
    u += 0x7fffu + ((u >> 16) & 1u);
    return (unsigned short)(u >> 16);
}
__device__ __forceinline__ float bf2f(unsigned short s) {
    unsigned u = (unsigned)s << 16;
    return __builtin_bit_cast(float, u);
}

// ---------------------------------------------------------------------------
// GEMM: Cout[M, 512] = A[M, K] @ W[512, K]^T + b1 + b2   (fp32, vector ALU)
// BM=BN=128, BK=16, 256 threads, 8x8 micro-tile.  (unchanged, proven)
// ---------------------------------------------------------------------------
template<int K>
__global__ __launch_bounds__(256, 2) void gemm_bias_kernel(
    const float* __restrict__ A, const float* __restrict__ W,
    const float* __restrict__ b1, const float* __restrict__ b2,
    float* __restrict__ Cout)
{
    __shared__ alignas(16) float As[16][132];
    __shared__ alignas(16) float Ws[16][132];

    const int tid = threadIdx.x;
    const int m0 = blockIdx.x * 128;
    const int n0 = blockIdx.y * 128;
    const int tx = tid & 15;
    const int ty = tid >> 4;

    float acc[8][8];
#pragma unroll
    for (int i = 0; i < 8; i++)
#pragma unroll
        for (int j = 0; j < 8; j++) acc[i][j] = 0.f;

    for (int k0 = 0; k0 < K; k0 += 16) {
#pragma unroll
        for (int i = 0; i < 2; i++) {
            int f = tid + 256 * i;
            int m = f >> 2, k4 = (f & 3) * 4;
            float4 v = *(const float4*)(A + (size_t)(m0 + m) * K + k0 + k4);
            As[k4 + 0][m] = v.x; As[k4 + 1][m] = v.y;
            As[k4 + 2][m] = v.z; As[k4 + 3][m] = v.w;
        }
#pragma unroll
        for (int i = 0; i < 2; i++) {
            int f = tid + 256 * i;
            int n = f >> 2, k4 = (f & 3) * 4;
            float4 v = *(const float4*)(W + (size_t)(n0 + n) * K + k0 + k4);
            Ws[k4 + 0][n] = v.x; Ws[k4 + 1][n] = v.y;
            Ws[k4 + 2][n] = v.z; Ws[k4 + 3][n] = v.w;
        }
        __syncthreads();

#pragma unroll
        for (int kk = 0; kk < 16; kk++) {
            float4 a0 = *(const float4*)&As[kk][ty * 8];
            float4 a1 = *(const float4*)&As[kk][ty * 8 + 4];
            float4 w0 = *(const float4*)&Ws[kk][tx * 8];
            float4 w1 = *(const float4*)&Ws[kk][tx * 8 + 4];
            float a[8] = {a0.x, a0.y, a0.z, a0.w, a1.x, a1.y, a1.z, a1.w};
            float w[8] = {w0.x, w0.y, w0.z, w0.w, w1.x, w1.y, w1.z, w1.w};
#pragma unroll
            for (int i = 0; i < 8; i++)
#pragma unroll
                for (int j = 0; j < 8; j++)
                    acc[i][j] = fmaf(a[i], w[j], acc[i][j]);
        }
        __syncthreads();
    }

    float bias[8];
#pragma unroll
    for (int j = 0; j < 8; j++) {
        int n = n0 + tx * 8 + j;
        bias[j] = b1[n] + b2[n];
    }
#pragma unroll
    for (int i = 0; i < 8; i++) {
        int m = m0 + ty * 8 + i;
        float4 v0 = {acc[i][0] + bias[0], acc[i][1] + bias[1],
                     acc[i][2] + bias[2], acc[i][3] + bias[3]};
        float4 v1 = {acc[i][4] + bias[4], acc[i][5] + bias[5],
                     acc[i][6] + bias[6], acc[i][7] + bias[7]};
        *(float4*)(Cout + (size_t)m * H_ + n0 + tx * 8)     = v0;
        *(float4*)(Cout + (size_t)m * H_ + n0 + tx * 8 + 4) = v1;
    }
}

// ---------------------------------------------------------------------------
// Team-parallel recurrent scan — round-11: split-bf16 MFMA inner product.
//
// Transport/barrier skeleton: EXACT round-9 (674 us proven). h moves via
// RELAXED agent-scope atomics on `data`; __syncthreads() drains vmcnt(0)
// before lane 0 signals; r5/r7-proven monotonic fetch_add counter; proj(t+1)
// prefetch rides the spin. (Round-10's A/B phase split REVERTED: each extra
// barrier round costs ~2k cycles — it added latency instead of hiding it.)
//
// Compute change: the 16x-broadcast ds_read_b128 h-reads (512 b128/CU/step,
// ~4-6k cycles of LDS return BW — the real round-9 bottleneck; bank-conflict
// counter was 0 because broadcasts dedup banks, not return bandwidth) are
// replaced by MFMA, which broadcasts operands inside the matrix unit.
//
// Numerics: split-bf16. h = hi + lo (each bf16), W_hh pre-split likewise
// (register-stationary B-frags). h*W ~ hi*Whi + hi*Wlo + lo*Whi, fp32 MFMA
// accumulation -> ~2^-16 relative error per product, comparable to fp32.
//
// Decomposition per block: [8 rows x NS=32 cols] x k=512.
//   wave wv: n-tile = wv>>1 (16 cols), k-half = (wv&1)*256 (8 MFMA k-steps).
//   MFMA 16x16x32: A rows 8-15 read duplicate LDS rows (row&7) -> acc rows
//   8-15 are copies, discarded. Cross-wave k-half reduce through red[4][8][16].
// LDS: h staged as hi/lo bf16 [8][512], XOR-swizzled (byte ^= row<<4) to kill
// the 1KB-row-stride 32-way bank conflict on A-frag reads (G4). Write side
// (reg-staged ds_write) uses the same XOR — both-sides-or-neither (rule 21).
// ---------------------------------------------------------------------------
__global__ __launch_bounds__(256, 2) void scan_team_kernel(
    float* __restrict__ data, const float* __restrict__ Whh,
    unsigned int* __restrict__ bar, int gen0)
{
    __shared__ alignas(16) unsigned short hs_hi[BS * H_];   // 8 KB
    __shared__ alignas(16) unsigned short hs_lo[BS * H_];   // 8 KB
    __shared__ alignas(16) float red[4][8][16];             // 2 KB

    const int tid   = threadIdx.x;
    const int team  = blockIdx.x & 31;   // members congruent mod 32 -> same XCD
    const int mem   = blockIdx.x >> 5;   // 0..15
    const int b0    = team * BS;
    const int n0    = mem * NS;
    const int lane  = tid & 63;
    const int wv    = tid >> 6;          // wave 0..3
    const int ntile = wv >> 1;           // 0: cols n0+0..15, 1: cols n0+16..31
    const int khalf = (wv & 1) << 8;     // k in [khalf, khalf+256)

    unsigned int* cnt = bar + team * 16;   // 64 B line per team

    // ---- W fragments: B-operand [k][n] = Whh[n][k], split-bf16 hi/lo ----
    // B-frag layout (16x16x32): col = lane&15, k = (lane>>4)*8 + j.
    bf16x8 bhi[8], blo[8];
    {
        const int wrow = n0 + (ntile << 4) + (lane & 15);
        const int koct = (lane >> 4) << 3;
#pragma unroll
        for (int ks = 0; ks < 8; ks++) {
            const float* wp = Whh + (size_t)wrow * H_ + khalf + ks * 32 + koct;
            float4 wa = *(const float4*)wp;
            float4 wb = *(const float4*)(wp + 4);
            float f[8] = {wa.x, wa.y, wa.z, wa.w, wb.x, wb.y, wb.z, wb.w};
#pragma unroll
            for (int j = 0; j < 8; j++) {
                unsigned short hi = f2bf_rn(f[j]);
                unsigned short lo = f2bf_rn(f[j] - bf2f(hi));
                bhi[ks][j] = (short)hi;
                blo[ks][j] = (short)lo;
            }
        }
    }

    // per-thread output pointer (1 of 8x32 per step) + t=0 proj prefetch
    float* pptr = data + ((size_t)(b0 + (tid >> 5)) * T_) * H_ + n0 + (tid & 31);
    float projv = *pptr;

    // A-frag read address pieces. A layout: row = lane&15 (we map 8-15 -> 0-7,
    // duplicates discarded), k = (lane>>4)*8 + j.
    const int arow  = lane & 7;
    const int rbase = arow << 10;        // row * 1024 bytes
    const int kxor  = arow << 4;         // swizzle XOR (bits 4-6)
    const int klane = (lane >> 4) << 4;  // k-octet byte offset

    for (int t = 0; t < T_; t++) {
        // ---- stage h_{t-1} as split-bf16 into swizzled LDS ----
        if (t == 0) {
#pragma unroll
            for (int i = 0; i < 2; i++) {
                ((float4*)hs_hi)[tid + 256 * i] = float4{0.f, 0.f, 0.f, 0.f};
                ((float4*)hs_lo)[tid + 256 * i] = float4{0.f, 0.f, 0.f, 0.f};
            }
        } else {
            const float* sp = data + ((size_t)b0 * T_ + (t - 1)) * H_;
#pragma unroll
            for (int b = 0; b < BS; b++) {
                unsigned long long v = __hip_atomic_load(
                    (const unsigned long long*)(sp + (size_t)b * T_ * H_) + tid,
                    __ATOMIC_RELAXED, __HIP_MEMORY_SCOPE_AGENT);
                union { unsigned long long q; float f[2]; } u; u.q = v;
                unsigned short h0 = f2bf_rn(u.f[0]);
                unsigned short h1 = f2bf_rn(u.f[1]);
                unsigned short l0 = f2bf_rn(u.f[0] - bf2f(h0));
                unsigned short l1 = f2bf_rn(u.f[1] - bf2f(h1));
                // element pair k = 2*tid of row b: byte = b*1024 + tid*4,
                // swizzled: ^ (b<<4) (bits 4-6 only; 4B alignment preserved)
                const int addr = ((b << 10) | (tid << 2)) ^ (b << 4);
                *(unsigned int*)((char*)hs_hi + addr) =
                    (unsigned int)h0 | ((unsigned int)h1 << 16);
                *(unsigned int*)((char*)hs_lo + addr) =
                    (unsigned int)l0 | ((unsigned int)l1 << 16);
            }
        }
        __syncthreads();

        // ---- MFMA over this wave's k-half: 8 k-steps x {hihi, hilo, lohi} ----
        f32x4 acc0 = {0.f, 0.f, 0.f, 0.f}, acc1 = {0.f, 0.f, 0.f, 0.f};
#pragma unroll
        for (int ks = 0; ks < 8; ks++) {
            const int kbyte = (khalf << 1) + ks * 64 + klane;
            const int addr  = rbase | (kbyte ^ kxor);
            bf16x8 ahi = *(const bf16x8*)((const char*)hs_hi + addr);
            bf16x8 alo = *(const bf16x8*)((const char*)hs_lo + addr);
            if ((ks & 1) == 0) {
                acc0 = __builtin_amdgcn_mfma_f32_16x16x32_bf16(ahi, bhi[ks], acc0, 0, 0, 0);
                acc0 = __builtin_amdgcn_mfma_f32_16x16x32_bf16(ahi, blo[ks], acc0, 0, 0, 0);
                acc0 = __builtin_amdgcn_mfma_f32_16x16x32_bf16(alo, bhi[ks], acc0, 0, 0, 0);
            } else {
                acc1 = __builtin_amdgcn_mfma_f32_16x16x32_bf16(ahi, bhi[ks], acc1, 0, 0, 0);
                acc1 = __builtin_amdgcn_mfma_f32_16x16x32_bf16(ahi, blo[ks], acc1, 0, 0, 0);
                acc1 = __builtin_amdgcn_mfma_f32_16x16x32_bf16(alo, bhi[ks], acc1, 0, 0, 0);
            }
        }

        // ---- cross-wave k-half reduce. C/D: col=lane&15, row=(lane>>4)*4+reg;
        // rows 0-7 live in lanes 0-31 (rows 8-15 are discarded duplicates).
        if (lane < 32) {
            const int rrow = (lane >> 4) << 2;
            const int col  = lane & 15;
#pragma unroll
            for (int r = 0; r < 4; r++)
                red[wv][rrow + r][col] = acc0[r] + acc1[r];
        }
        __syncthreads();

        // ---- epilogue: 1 output/thread; sum the two k-halves ----
        {
            const int bb = tid >> 5, n2 = tid & 31;
            const int nt2 = (n2 >> 4) << 1;   // {0,1}->red[0]+red[1], {2,3}
            float s = red[nt2][bb][n2 & 15] + red[nt2 + 1][bb][n2 & 15];
            float h = fmaxf(s + projv, 0.f);
            __hip_atomic_store(pptr, h,
                               __ATOMIC_RELAXED, __HIP_MEMORY_SCOPE_AGENT);
        }
        pptr += H_;

        // ---- team barrier (r5/r7-proven); proj(t+1) prefetch rides the spin
        if (t < T_ - 1) {
            __syncthreads();   // drains vmcnt(0): h-stores visible before signal
            if (tid == 0)
                __hip_atomic_fetch_add(cnt, 1u,
                                       __ATOMIC_RELAXED, __HIP_MEMORY_SCOPE_AGENT);
            float nextproj = *pptr;          // in flight during the spin
            if (tid == 0) {
                const unsigned target = (unsigned)TB * (unsigned)(gen0 + t + 1);
                while (__hip_atomic_load(cnt, __ATOMIC_RELAXED,
                                         __HIP_MEMORY_SCOPE_AGENT) < target) {
                    __builtin_amdgcn_s_sleep(2);
                }
            }
            __syncthreads();   // release block; prefetch drains here too
            projv = nextproj;
        }
    }
}

// ---------------------------------------------------------------------------
// FC head: out[b][c] = sum_i h1[b][i] * Wfc[c][i] + bfc[c]   (unchanged)
// ---------------------------------------------------------------------------
__global__ __launch_bounds__(256) void fc_kernel(
    const float* __restrict__ Hl, const float* __restrict__ Wfc,
    const float* __restrict__ bfc, float* __restrict__ out)
{
    const int b = blockIdx.x;
    const int tid = threadIdx.x;
    const float* hb = Hl + (size_t)b * (T_ * H_);

    float acc[C_];
#pragma unroll
    for (int c = 0; c < C_; c++) acc[c] = 0.f;

    for (int i = tid * 4; i < T_ * H_; i += 256 * 4) {
        float4 hv = *(const float4*)(hb + i);
#pragma unroll
        for (int c = 0; c < C_; c++) {
            float4 wv = *(const float4*)(Wfc + (size_t)c * (T_ * H_) + i);
            acc[c] = fmaf(hv.x, wv.x, fmaf(hv.y, wv.y,
                     fmaf(hv.z, wv.z, fmaf(hv.w, wv.w, acc[c]))));
        }
    }

    __shared__ float red[4][C_];
#pragma unroll
    for (int c = 0; c < C_; c++) {
        float v = acc[c];
#pragma unroll
        for (int off = 32; off >= 1; off >>= 1) v += __shfl_xor(v, off, 64);
        if ((tid & 63) == 0) red[tid >> 6][c] = v;
    }
    __syncthreads();
    if (tid < C_) {
        float v = red[0][tid] + red[1][tid] + red[2][tid] + red[3][tid] + bfc[tid];
        out[(size_t)b * C_ + tid] = v;
    }
}

// ---------------------------------------------------------------------------
// Pipeline: proj0 GEMM -> scan0 -> proj1 GEMM -> scan1 -> FC.
// Team counters: 32 teams x 64 B lines in the first 2 KB of d_out (zeroed by
// hipMemsetAsync — graph-safe; fc_kernel fully overwrites d_out at the end).
// Monotonic counters shared across both scans: scan0 targets TB*(t+1) (last
// step skips the barrier, ending at TB*127), scan1 uses gen0=127 to continue.
// ---------------------------------------------------------------------------
extern "C" void kernel_launch(void* const* d_in, const int* in_sizes, int n_in,
                              void* d_out, int out_size, void* d_ws, size_t ws_size,
                              hipStream_t stream)
{
    (void)in_sizes; (void)n_in; (void)out_size; (void)ws_size;

    const float* x    = (const float*)d_in[0];
    const float* Wih0 = (const float*)d_in[1];
    const float* Whh0 = (const float*)d_in[2];
    const float* bih0 = (const float*)d_in[3];
    const float* bhh0 = (const float*)d_in[4];
    const float* Wih1 = (const float*)d_in[5];
    const float* Whh1 = (const float*)d_in[6];
    const float* bih1 = (const float*)d_in[7];
    const float* bhh1 = (const float*)d_in[8];
    const float* Wfc  = (const float*)d_in[9];
    const float* bfc  = (const float*)d_in[10];
    float* out = (float*)d_out;

    float* ws0 = (float*)d_ws;                    // [B][T][H] proj0 -> h0
    float* ws1 = ws0 + (size_t)B_ * T_ * H_;      // [B][T][H] proj1 -> h1
    unsigned int* bar = (unsigned int*)d_out;     // TEAMS x 16-dword lines

    hipMemsetAsync(bar, 0, TEAMS * 16 * sizeof(unsigned int), stream);

    dim3 gproj(B_ * T_ / 128, H_ / 128);   // (256, 4)

    gemm_bias_kernel<F_><<<gproj, 256, 0, stream>>>(x, Wih0, bih0, bhh0, ws0);
    scan_team_kernel<<<TEAMS * TB, 256, 0, stream>>>(ws0, Whh0, bar, 0);

    gemm_bias_kernel<H_><<<gproj, 256, 0, stream>>>(ws0, Wih1, bih1, bhh1, ws1);
    scan_team_kernel<<<TEAMS * TB, 256, 0, stream>>>(ws1, Whh1, bar, T_ - 1);

    fc_kernel<<<B_, 256, 0, stream>>>(ws1, Wfc, bfc, out);
}

// Round 3
// 1411.165 us; speedup vs baseline: 1.3435x; 1.0291x over previous
//
#include <hip/hip_runtime.h>
#include <cstddef>

#define B_ 256
#define T_ 128
#define F_ 256
#define H_ 512
#define C_ 10

#define TEAMS 32     // teams; team owns BS batch rows
#define TB    8      // blocks per team (round-12: was 16) -> 256 blocks = 1/CU
#define BS    8      // batch rows per team
#define NS    64     // n columns per member block (round-12: was 32)

typedef short bf16x8 __attribute__((ext_vector_type(8)));
typedef float f32x4  __attribute__((ext_vector_type(4)));

// round-to-nearest-even fp32 -> bf16
__device__ __forceinline__ unsigned short f2bf_rn(float f) {
    unsigned u = __builtin_bit_cast(unsigned, f);
    u += 0x7fffu + ((u >> 16) & 1u);
    return (unsigned short)(u >> 16);
}
__device__ __forceinline__ float bf2f(unsigned short s) {
    unsigned u = (unsigned)s << 16;
    return __builtin_bit_cast(float, u);
}

// ---------------------------------------------------------------------------
// GEMM: Cout[M, 512] = A[M, K] @ W[512, K]^T + b1 + b2   (fp32, vector ALU)
// BM=BN=128, BK=16, 256 threads, 8x8 micro-tile.  (unchanged, proven)
// ---------------------------------------------------------------------------
template<int K>
__global__ __launch_bounds__(256, 2) void gemm_bias_kernel(
    const float* __restrict__ A, const float* __restrict__ W,
    const float* __restrict__ b1, const float* __restrict__ b2,
    float* __restrict__ Cout)
{
    __shared__ alignas(16) float As[16][132];
    __shared__ alignas(16) float Ws[16][132];

    const int tid = threadIdx.x;
    const int m0 = blockIdx.x * 128;
    const int n0 = blockIdx.y * 128;
    const int tx = tid & 15;
    const int ty = tid >> 4;

    float acc[8][8];
#pragma unroll
    for (int i = 0; i < 8; i++)
#pragma unroll
        for (int j = 0; j < 8; j++) acc[i][j] = 0.f;

    for (int k0 = 0; k0 < K; k0 += 16) {
#pragma unroll
        for (int i = 0; i < 2; i++) {
            int f = tid + 256 * i;
            int m = f >> 2, k4 = (f & 3) * 4;
            float4 v = *(const float4*)(A + (size_t)(m0 + m) * K + k0 + k4);
            As[k4 + 0][m] = v.x; As[k4 + 1][m] = v.y;
            As[k4 + 2][m] = v.z; As[k4 + 3][m] = v.w;
        }
#pragma unroll
        for (int i = 0; i < 2; i++) {
            int f = tid + 256 * i;
            int n = f >> 2, k4 = (f & 3) * 4;
            float4 v = *(const float4*)(W + (size_t)(n0 + n) * K + k0 + k4);
            Ws[k4 + 0][n] = v.x; Ws[k4 + 1][n] = v.y;
            Ws[k4 + 2][n] = v.z; Ws[k4 + 3][n] = v.w;
        }
        __syncthreads();

#pragma unroll
        for (int kk = 0; kk < 16; kk++) {
            float4 a0 = *(const float4*)&As[kk][ty * 8];
            float4 a1 = *(const float4*)&As[kk][ty * 8 + 4];
            float4 w0 = *(const float4*)&Ws[kk][tx * 8];
            float4 w1 = *(const float4*)&Ws[kk][tx * 8 + 4];
            float a[8] = {a0.x, a0.y, a0.z, a0.w, a1.x, a1.y, a1.z, a1.w};
            float w[8] = {w0.x, w0.y, w0.z, w0.w, w1.x, w1.y, w1.z, w1.w};
#pragma unroll
            for (int i = 0; i < 8; i++)
#pragma unroll
                for (int j = 0; j < 8; j++)
                    acc[i][j] = fmaf(a[i], w[j], acc[i][j]);
        }
        __syncthreads();
    }

    float bias[8];
#pragma unroll
    for (int j = 0; j < 8; j++) {
        int n = n0 + tx * 8 + j;
        bias[j] = b1[n] + b2[n];
    }
#pragma unroll
    for (int i = 0; i < 8; i++) {
        int m = m0 + ty * 8 + i;
        float4 v0 = {acc[i][0] + bias[0], acc[i][1] + bias[1],
                     acc[i][2] + bias[2], acc[i][3] + bias[3]};
        float4 v1 = {acc[i][4] + bias[4], acc[i][5] + bias[5],
                     acc[i][6] + bias[6], acc[i][7] + bias[7]};
        *(float4*)(Cout + (size_t)m * H_ + n0 + tx * 8)     = v0;
        *(float4*)(Cout + (size_t)m * H_ + n0 + tx * 8 + 4) = v1;
    }
}

// ---------------------------------------------------------------------------
// Team-parallel recurrent scan — round-12: 8-member teams, full-k waves,
// 1 block/CU.
//
// Transport/barrier skeleton: EXACT round-9/11 proven primitives. h moves via
// RELAXED agent-scope atomics on `data`; __syncthreads() drains vmcnt(0)
// before lane 0 signals; monotonic fetch_add counter (flag+ballot banned);
// proj(t+1) prefetch rides the spin.
//
// Round-12 structural change (attacks the ~10k-cycle/step residual that
// round-11 exposed as NOT compute): TB 16->8, NS 32->64, grid 512->256
// blocks = exactly 1 block/CU on 8 XCDs (team = blockIdx&31 keeps all
// members of a team on one XCD: XCD = blockIdx%8 = team%8).
//   - no co-resident block -> tid==0 signal/spin wave never contends
//   - barrier fan-in halves: 8 RMWs + 8 spinners per team line
//   - each wave owns 16 cols x FULL k=512 -> cross-wave red[] reduce and its
//     __syncthreads removed: 3 syncs/step instead of 4
//   - team h-reload L2 traffic halves (8 members x 16KB vs 16 x 16KB)
// W_hh B-frags: 16 ks x {hi,lo} = 128 VGPRs, register-stationary
// (__launch_bounds__(256,1): 1 block/CU is the design point anyway).
// MFMA chains: 4 independent accumulators (ks&3, static under full unroll),
// summed pairwise at the end.
// LDS swizzle unchanged (byte ^= row<<4; write-side matches read-side).
// ---------------------------------------------------------------------------
__global__ __launch_bounds__(256, 1) void scan_team_kernel(
    float* __restrict__ data, const float* __restrict__ Whh,
    unsigned int* __restrict__ bar, int gen0)
{
    __shared__ alignas(16) unsigned short hs_hi[BS * H_];   // 8 KB
    __shared__ alignas(16) unsigned short hs_lo[BS * H_];   // 8 KB

    const int tid   = threadIdx.x;
    const int team  = blockIdx.x & 31;   // members stride 32 -> same XCD
    const int mem   = blockIdx.x >> 5;   // 0..7
    const int b0    = team * BS;
    const int n0    = mem * NS;
    const int lane  = tid & 63;
    const int wv    = tid >> 6;          // wave 0..3: cols n0+wv*16..+15, full k

    unsigned int* cnt = bar + team * 16;   // 64 B line per team

    // ---- W fragments: B-operand [k][n] = Whh[n][k], split-bf16 hi/lo ----
    // B-frag layout (16x16x32): col = lane&15, k = ks*32 + (lane>>4)*8 + j.
    bf16x8 bhi[16], blo[16];
    {
        const int wrow = n0 + (wv << 4) + (lane & 15);
        const int koct = (lane >> 4) << 3;
#pragma unroll
        for (int ks = 0; ks < 16; ks++) {
            const float* wp = Whh + (size_t)wrow * H_ + ks * 32 + koct;
            const unsigned long long* q = (const unsigned long long*)wp;
            float f[8];
#pragma unroll
            for (int j = 0; j < 4; j++) {
                union { unsigned long long q; float f[2]; } u;
                u.q = __hip_atomic_load(q + j, __ATOMIC_RELAXED,
                                        __HIP_MEMORY_SCOPE_AGENT);
                f[2 * j] = u.f[0]; f[2 * j + 1] = u.f[1];
            }
#pragma unroll
            for (int j = 0; j < 8; j++) {
                unsigned short hi = f2bf_rn(f[j]);
                unsigned short lo = f2bf_rn(f[j] - bf2f(hi));
                bhi[ks][j] = (short)hi;
                blo[ks][j] = (short)lo;
            }
        }
    }

    // ---- output/proj pointers: lanes 0-31 of each wave own 4 outputs ----
    // C/D: col = lane&15 (output col), row m = (lane>>4)*4 + r (batch row).
    // Lanes 32-63 hold duplicate rows (A rows 8-15 == 0-7), masked off.
    const int orow = ((lane >> 4) & 1) << 2;   // 0 or 4
    const int ocol = (wv << 4) + (lane & 15);
    float* pout = data + (size_t)(b0 + orow) * T_ * H_ + n0 + ocol;
    float proj[4];
    if (lane < 32) {
#pragma unroll
        for (int r = 0; r < 4; r++)
            proj[r] = pout[(size_t)r * T_ * H_];   // t=0 prefetch
    }

    // A-frag read address pieces (row = lane&7, duplicates for lanes' row&8)
    const int arow  = lane & 7;
    const int rbase = arow << 10;        // row * 1024 bytes
    const int kxor  = arow << 4;         // swizzle XOR (bits 4-6)
    const int klane = (lane >> 4) << 4;  // k-slice byte offset within 64B

    for (int t = 0; t < T_; t++) {
        // ---- stage h_{t-1} as split-bf16 into swizzled LDS ----
        if (t == 0) {
#pragma unroll
            for (int i = 0; i < 2; i++) {
                ((float4*)hs_hi)[tid + 256 * i] = float4{0.f, 0.f, 0.f, 0.f};
                ((float4*)hs_lo)[tid + 256 * i] = float4{0.f, 0.f, 0.f, 0.f};
            }
        } else {
            const float* sp = data + ((size_t)b0 * T_ + (t - 1)) * H_;
#pragma unroll
            for (int b = 0; b < BS; b++) {
                unsigned long long v = __hip_atomic_load(
                    (const unsigned long long*)(sp + (size_t)b * T_ * H_) + tid,
                    __ATOMIC_RELAXED, __HIP_MEMORY_SCOPE_AGENT);
                union { unsigned long long q; float f[2]; } u; u.q = v;
                unsigned short h0 = f2bf_rn(u.f[0]);
                unsigned short h1 = f2bf_rn(u.f[1]);
                unsigned short l0 = f2bf_rn(u.f[0] - bf2f(h0));
                unsigned short l1 = f2bf_rn(u.f[1] - bf2f(h1));
                const int addr = ((b << 10) | (tid << 2)) ^ (b << 4);
                *(unsigned int*)((char*)hs_hi + addr) =
                    (unsigned int)h0 | ((unsigned int)h1 << 16);
                *(unsigned int*)((char*)hs_lo + addr) =
                    (unsigned int)l0 | ((unsigned int)l1 << 16);
            }
        }
        __syncthreads();

        // ---- MFMA, full k: 16 ks x {hihi, hilo, lohi}, 4 acc chains ----
        f32x4 acc[4];
#pragma unroll
        for (int i = 0; i < 4; i++) acc[i] = f32x4{0.f, 0.f, 0.f, 0.f};
#pragma unroll
        for (int ks = 0; ks < 16; ks++) {
            const int kbyte = ks * 64 + klane;
            const int addr  = rbase | (kbyte ^ kxor);
            bf16x8 ahi = *(const bf16x8*)((const char*)hs_hi + addr);
            bf16x8 alo = *(const bf16x8*)((const char*)hs_lo + addr);
            const int c = ks & 3;   // static after unroll (rule 20)
            acc[c] = __builtin_amdgcn_mfma_f32_16x16x32_bf16(ahi, bhi[ks], acc[c], 0, 0, 0);
            acc[c] = __builtin_amdgcn_mfma_f32_16x16x32_bf16(ahi, blo[ks], acc[c], 0, 0, 0);
            acc[c] = __builtin_amdgcn_mfma_f32_16x16x32_bf16(alo, bhi[ks], acc[c], 0, 0, 0);
        }
        f32x4 s01 = acc[0] + acc[1];
        f32x4 s23 = acc[2] + acc[3];
        f32x4 sum = s01 + s23;

        // ---- epilogue: lanes 0-31 write 4 outputs each (own cols/rows) ----
        if (lane < 32) {
            float* pt = pout + (size_t)t * H_;
#pragma unroll
            for (int r = 0; r < 4; r++) {
                float h = fmaxf(sum[r] + proj[r], 0.f);
                __hip_atomic_store(pt + (size_t)r * T_ * H_, h,
                                   __ATOMIC_RELAXED, __HIP_MEMORY_SCOPE_AGENT);
            }
        }

        // ---- team barrier; proj(t+1) prefetch rides the spin ----
        if (t < T_ - 1) {
            __syncthreads();   // drains vmcnt(0): h-stores visible pre-signal
            if (tid == 0)
                __hip_atomic_fetch_add(cnt, 1u,
                                       __ATOMIC_RELAXED, __HIP_MEMORY_SCOPE_AGENT);
            if (lane < 32) {
                float* pn = pout + (size_t)(t + 1) * H_;
#pragma unroll
                for (int r = 0; r < 4; r++)
                    proj[r] = pn[(size_t)r * T_ * H_];   // in flight during spin
            }
            if (tid == 0) {
                const unsigned target = (unsigned)TB * (unsigned)(gen0 + t + 1);
                while (__hip_atomic_load(cnt, __ATOMIC_RELAXED,
                                         __HIP_MEMORY_SCOPE_AGENT) < target) {
                    __builtin_amdgcn_s_sleep(1);
                }
            }
            __syncthreads();   // release block; prefetch drains here too
        }
    }
}

// ---------------------------------------------------------------------------
// FC head: out[b][c] = sum_i h1[b][i] * Wfc[c][i] + bfc[c]   (unchanged)
// ---------------------------------------------------------------------------
__global__ __launch_bounds__(256) void fc_kernel(
    const float* __restrict__ Hl, const float* __restrict__ Wfc,
    const float* __restrict__ bfc, float* __restrict__ out)
{
    const int b = blockIdx.x;
    const int tid = threadIdx.x;
    const float* hb = Hl + (size_t)b * (T_ * H_);

    float acc[C_];
#pragma unroll
    for (int c = 0; c < C_; c++) acc[c] = 0.f;

    for (int i = tid * 4; i < T_ * H_; i += 256 * 4) {
        float4 hv = *(const float4*)(hb + i);
#pragma unroll
        for (int c = 0; c < C_; c++) {
            float4 wv = *(const float4*)(Wfc + (size_t)c * (T_ * H_) + i);
            acc[c] = fmaf(hv.x, wv.x, fmaf(hv.y, wv.y,
                     fmaf(hv.z, wv.z, fmaf(hv.w, wv.w, acc[c]))));
        }
    }

    __shared__ float red[4][C_];
#pragma unroll
    for (int c = 0; c < C_; c++) {
        float v = acc[c];
#pragma unroll
        for (int off = 32; off >= 1; off >>= 1) v += __shfl_xor(v, off, 64);
        if ((tid & 63) == 0) red[tid >> 6][c] = v;
    }
    __syncthreads();
    if (tid < C_) {
        float v = red[0][tid] + red[1][tid] + red[2][tid] + red[3][tid] + bfc[tid];
        out[(size_t)b * C_ + tid] = v;
    }
}

// ---------------------------------------------------------------------------
// Pipeline: proj0 GEMM -> scan0 -> proj1 GEMM -> scan1 -> FC.
// Team counters: 32 teams x 64 B lines in the first 2 KB of d_out (zeroed by
// hipMemsetAsync — graph-safe; fc_kernel fully overwrites d_out at the end).
// Monotonic counters shared across both scans: scan0 targets TB*(t+1) (last
// step skips the barrier, ending at TB*127), scan1 uses gen0=127 to continue.
// ---------------------------------------------------------------------------
extern "C" void kernel_launch(void* const* d_in, const int* in_sizes, int n_in,
                              void* d_out, int out_size, void* d_ws, size_t ws_size,
                              hipStream_t stream)
{
    (void)in_sizes; (void)n_in; (void)out_size; (void)ws_size;

    const float* x    = (const float*)d_in[0];
    const float* Wih0 = (const float*)d_in[1];
    const float* Whh0 = (const float*)d_in[2];
    const float* bih0 = (const float*)d_in[3];
    const float* bhh0 = (const float*)d_in[4];
    const float* Wih1 = (const float*)d_in[5];
    const float* Whh1 = (const float*)d_in[6];
    const float* bih1 = (const float*)d_in[7];
    const float* bhh1 = (const float*)d_in[8];
    const float* Wfc  = (const float*)d_in[9];
    const float* bfc  = (const float*)d_in[10];
    float* out = (float*)d_out;

    float* ws0 = (float*)d_ws;                    // [B][T][H] proj0 -> h0
    float* ws1 = ws0 + (size_t)B_ * T_ * H_;      // [B][T][H] proj1 -> h1
    unsigned int* bar = (unsigned int*)d_out;     // TEAMS x 16-dword lines

    hipMemsetAsync(bar, 0, TEAMS * 16 * sizeof(unsigned int), stream);

    dim3 gproj(B_ * T_ / 128, H_ / 128);   // (256, 4)

    gemm_bias_kernel<F_><<<gproj, 256, 0, stream>>>(x, Wih0, bih0, bhh0, ws0);
    scan_team_kernel<<<TEAMS * TB, 256, 0, stream>>>(ws0, Whh0, bar, 0);

    gemm_bias_kernel<H_><<<gproj, 256, 0, stream>>>(ws0, Wih1, bih1, bhh1, ws1);
    scan_team_kernel<<<TEAMS * TB, 256, 0, stream>>>(ws1, Whh1, bar, T_ - 1);

    fc_kernel<<<B_, 256, 0, stream>>>(ws1, Wfc, bfc, out);
}

// Round 4
// 1095.463 us; speedup vs baseline: 1.7307x; 1.2882x over previous
//
#include <hip/hip_runtime.h>
#include <cstddef>

#define B_ 256
#define T_ 128
#define F_ 256
#define H_ 512
#define C_ 10

#define TEAMS 32     // teams; team owns BS batch rows
#define TB    16     // blocks per team (round-13: back to 16, NS=32 geometry)
#define BS    8      // batch rows per team
#define NS    32     // n columns per member block

typedef short bf16x8 __attribute__((ext_vector_type(8)));
typedef float f32x4  __attribute__((ext_vector_type(4)));

// round-to-nearest-even fp32 -> bf16
__device__ __forceinline__ unsigned short f2bf_rn(float f) {
    unsigned u = __builtin_bit_cast(unsigned, f);
    u += 0x7fffu + ((u >> 16) & 1u);
    return (unsigned short)(u >> 16);
}
__device__ __forceinline__ float bf2f(unsigned short s) {
    unsigned u = (unsigned)s << 16;
    return __builtin_bit_cast(float, u);
}

// ---------------------------------------------------------------------------
// GEMM: Cout[M, 512] = A[M, K] @ W[512, K]^T + b1 + b2   (fp32, vector ALU)
// BM=BN=128, BK=16, 256 threads, 8x8 micro-tile.  (unchanged, proven)
// Only used for proj0 now (x @ W_ih0^T).
// ---------------------------------------------------------------------------
template<int K>
__global__ __launch_bounds__(256, 2) void gemm_bias_kernel(
    const float* __restrict__ A, const float* __restrict__ W,
    const float* __restrict__ b1, const float* __restrict__ b2,
    float* __restrict__ Cout)
{
    __shared__ alignas(16) float As[16][132];
    __shared__ alignas(16) float Ws[16][132];

    const int tid = threadIdx.x;
    const int m0 = blockIdx.x * 128;
    const int n0 = blockIdx.y * 128;
    const int tx = tid & 15;
    const int ty = tid >> 4;

    float acc[8][8];
#pragma unroll
    for (int i = 0; i < 8; i++)
#pragma unroll
        for (int j = 0; j < 8; j++) acc[i][j] = 0.f;

    for (int k0 = 0; k0 < K; k0 += 16) {
#pragma unroll
        for (int i = 0; i < 2; i++) {
            int f = tid + 256 * i;
            int m = f >> 2, k4 = (f & 3) * 4;
            float4 v = *(const float4*)(A + (size_t)(m0 + m) * K + k0 + k4);
            As[k4 + 0][m] = v.x; As[k4 + 1][m] = v.y;
            As[k4 + 2][m] = v.z; As[k4 + 3][m] = v.w;
        }
#pragma unroll
        for (int i = 0; i < 2; i++) {
            int f = tid + 256 * i;
            int n = f >> 2, k4 = (f & 3) * 4;
            float4 v = *(const float4*)(W + (size_t)(n0 + n) * K + k0 + k4);
            Ws[k4 + 0][n] = v.x; Ws[k4 + 1][n] = v.y;
            Ws[k4 + 2][n] = v.z; Ws[k4 + 3][n] = v.w;
        }
        __syncthreads();

#pragma unroll
        for (int kk = 0; kk < 16; kk++) {
            float4 a0 = *(const float4*)&As[kk][ty * 8];
            float4 a1 = *(const float4*)&As[kk][ty * 8 + 4];
            float4 w0 = *(const float4*)&Ws[kk][tx * 8];
            float4 w1 = *(const float4*)&Ws[kk][tx * 8 + 4];
            float a[8] = {a0.x, a0.y, a0.z, a0.w, a1.x, a1.y, a1.z, a1.w};
            float w[8] = {w0.x, w0.y, w0.z, w0.w, w1.x, w1.y, w1.z, w1.w};
#pragma unroll
            for (int i = 0; i < 8; i++)
#pragma unroll
                for (int j = 0; j < 8; j++)
                    acc[i][j] = fmaf(a[i], w[j], acc[i][j]);
        }
        __syncthreads();
    }

    float bias[8];
#pragma unroll
    for (int j = 0; j < 8; j++) {
        int n = n0 + tx * 8 + j;
        bias[j] = b1[n] + b2[n];
    }
#pragma unroll
    for (int i = 0; i < 8; i++) {
        int m = m0 + ty * 8 + i;
        float4 v0 = {acc[i][0] + bias[0], acc[i][1] + bias[1],
                     acc[i][2] + bias[2], acc[i][3] + bias[3]};
        float4 v1 = {acc[i][4] + bias[4], acc[i][5] + bias[5],
                     acc[i][6] + bias[6], acc[i][7] + bias[7]};
        *(float4*)(Cout + (size_t)m * H_ + n0 + tx * 8)     = v0;
        *(float4*)(Cout + (size_t)m * H_ + n0 + tx * 8 + 4) = v1;
    }
}

// ---------------------------------------------------------------------------
// W fragment loader: B-operand [k][n] = W[n][k], split-bf16 hi/lo, 8 ks.
// B-frag layout (16x16x32): col = lane&15, k = khalf + ks*32 + (lane>>4)*8+j.
// Atomic-pinned 8B loads (r7-proven pattern), one-time setup cost.
// ---------------------------------------------------------------------------
__device__ __forceinline__ void load_wfrag(
    const float* __restrict__ W, int wrow, int khalf, int koct,
    bf16x8* bhi, bf16x8* blo)
{
#pragma unroll
    for (int ks = 0; ks < 8; ks++) {
        const float* wp = W + (size_t)wrow * H_ + khalf + ks * 32 + koct;
        const unsigned long long* q = (const unsigned long long*)wp;
        float f[8];
#pragma unroll
        for (int j = 0; j < 4; j++) {
            union { unsigned long long q; float f[2]; } u;
            u.q = __hip_atomic_load(q + j, __ATOMIC_RELAXED,
                                    __HIP_MEMORY_SCOPE_AGENT);
            f[2 * j] = u.f[0]; f[2 * j + 1] = u.f[1];
        }
#pragma unroll
        for (int j = 0; j < 8; j++) {
            unsigned short hi = f2bf_rn(f[j]);
            unsigned short lo = f2bf_rn(f[j] - bf2f(hi));
            bhi[ks][j] = (short)hi;
            blo[ks][j] = (short)lo;
        }
    }
}

// ---------------------------------------------------------------------------
// Round-13: FUSED dual-layer scan, one barrier per round.
//
// Rounds r = 0..T_: round r computes
//   h0(r)   = relu(proj0(r) + Whh0 @ h0(r-1))            [r < T_]
//   h1(r-1) = relu(Wih1 @ h0(r-1) + b1i+b1h + Whh1 @ h1(r-2))   [r >= 1]
// Both published with ONE team barrier: 128 barrier rounds replace the
// previous 2 x 127 (two scans) + the proj1 GEMM dispatch. Rationale: r12
// showed the ~7.5k-cycle/step transport chain (store-drain -> L3 RMW ->
// spin-detect -> release -> reload) is a PER-ROUND latency, insensitive to
// fan-in/occupancy tuning; so pay it half as often. The 3 matmuls share the
// 2 staged LDS operands (h0 tile feeds both Whh0 and Wih1 products).
//
// Transport/barrier primitives byte-identical to the r5/r7/r9-proven set:
// relaxed agent-scope atomics on ws0/ws1, __syncthreads() drains vmcnt(0)
// before lane 0 signals, monotonic fetch_add counter (flag+ballot banned),
// proj0 prefetch rides the spin. ws1 is never read-before-write in a run
// (round r reads h1(r-2), written in round r-1).
//
// Geometry: r11-proven TB=16/NS=32. Wave wv: ntile=wv>>1 (16 cols),
// khalf=(wv&1)*256; k-half partials reduced via red0/red1 LDS.
// Weights: 3 matrices x 16 bf16x8 = 192 VGPR register-stationary.
// __launch_bounds__(256,2) FORCES vgpr<=256 -> 2 blocks/CU co-residency
// guaranteed (spills allowed, deadlock impossible). LDS 36KB (x2 = 72 <=160).
// ---------------------------------------------------------------------------
__global__ __launch_bounds__(256, 2) void fused_scan_kernel(
    float* __restrict__ ws0, float* __restrict__ ws1,
    const float* __restrict__ Whh0, const float* __restrict__ Wih1,
    const float* __restrict__ Whh1,
    const float* __restrict__ bih1, const float* __restrict__ bhh1,
    unsigned int* __restrict__ bar)
{
    __shared__ alignas(16) unsigned short hs0_hi[BS * H_];  // 8 KB
    __shared__ alignas(16) unsigned short hs0_lo[BS * H_];  // 8 KB
    __shared__ alignas(16) unsigned short hs1_hi[BS * H_];  // 8 KB
    __shared__ alignas(16) unsigned short hs1_lo[BS * H_];  // 8 KB
    __shared__ alignas(16) float red0[4][8][16];            // 2 KB
    __shared__ alignas(16) float red1[4][8][16];            // 2 KB

    const int tid   = threadIdx.x;
    const int team  = blockIdx.x & 31;   // members stride 32 -> same XCD
    const int mem   = blockIdx.x >> 5;   // 0..15
    const int b0    = team * BS;
    const int n0    = mem * NS;
    const int lane  = tid & 63;
    const int wv    = tid >> 6;          // wave 0..3
    const int khalf = (wv & 1) << 8;     // k in [khalf, khalf+256)

    unsigned int* cnt = bar + team * 16;   // 64 B line per team

    // ---- register-stationary weight fragments: 3 matrices, k-half each ----
    const int wrow = n0 + ((wv >> 1) << 4) + (lane & 15);
    const int koct = (lane >> 4) << 3;
    bf16x8 w0hi[8], w0lo[8], wihi[8], wilo[8], w1hi[8], w1lo[8];
    load_wfrag(Whh0, wrow, khalf, koct, w0hi, w0lo);
    load_wfrag(Wih1, wrow, khalf, koct, wihi, wilo);
    load_wfrag(Whh1, wrow, khalf, koct, w1hi, w1lo);

    // ---- per-thread output slot: row = tid>>5 (0..7), col = tid&31 ----
    float* p0 = ws0 + ((size_t)(b0 + (tid >> 5)) * T_) * H_ + n0 + (tid & 31);
    float* p1 = ws1 + ((size_t)(b0 + (tid >> 5)) * T_) * H_ + n0 + (tid & 31);
    float projv  = *p0;                                   // proj0(0) prefetch
    const float bias1v = bih1[n0 + (tid & 31)] + bhh1[n0 + (tid & 31)];

    // A-frag read address pieces (row = lane&7; lanes' bit3 rows duplicate)
    const int arow  = lane & 7;
    const int rbase = arow << 10;        // row * 1024 bytes
    const int kxor  = arow << 4;         // swizzle XOR (bits 4-6)
    const int klane = (lane >> 4) << 4;  // k-octet byte offset

    for (int r = 0; r <= T_; r++) {
        // ---- stage h0(r-1) and h1(r-2) as split-bf16 into swizzled LDS ----
        if (r == 0) {
#pragma unroll
            for (int i = 0; i < 2; i++) {
                ((float4*)hs0_hi)[tid + 256 * i] = float4{0.f, 0.f, 0.f, 0.f};
                ((float4*)hs0_lo)[tid + 256 * i] = float4{0.f, 0.f, 0.f, 0.f};
            }
        } else {
            const float* sp = ws0 + ((size_t)b0 * T_ + (r - 1)) * H_;
#pragma unroll
            for (int b = 0; b < BS; b++) {
                unsigned long long v = __hip_atomic_load(
                    (const unsigned long long*)(sp + (size_t)b * T_ * H_) + tid,
                    __ATOMIC_RELAXED, __HIP_MEMORY_SCOPE_AGENT);
                union { unsigned long long q; float f[2]; } u; u.q = v;
                unsigned short h0 = f2bf_rn(u.f[0]);
                unsigned short h1 = f2bf_rn(u.f[1]);
                unsigned short l0 = f2bf_rn(u.f[0] - bf2f(h0));
                unsigned short l1 = f2bf_rn(u.f[1] - bf2f(h1));
                const int addr = ((b << 10) | (tid << 2)) ^ (b << 4);
                *(unsigned int*)((char*)hs0_hi + addr) =
                    (unsigned int)h0 | ((unsigned int)h1 << 16);
                *(unsigned int*)((char*)hs0_lo + addr) =
                    (unsigned int)l0 | ((unsigned int)l1 << 16);
            }
        }
        if (r <= 1) {
#pragma unroll
            for (int i = 0; i < 2; i++) {
                ((float4*)hs1_hi)[tid + 256 * i] = float4{0.f, 0.f, 0.f, 0.f};
                ((float4*)hs1_lo)[tid + 256 * i] = float4{0.f, 0.f, 0.f, 0.f};
            }
        } else {
            const float* sp = ws1 + ((size_t)b0 * T_ + (r - 2)) * H_;
#pragma unroll
            for (int b = 0; b < BS; b++) {
                unsigned long long v = __hip_atomic_load(
                    (const unsigned long long*)(sp + (size_t)b * T_ * H_) + tid,
                    __ATOMIC_RELAXED, __HIP_MEMORY_SCOPE_AGENT);
                union { unsigned long long q; float f[2]; } u; u.q = v;
                unsigned short h0 = f2bf_rn(u.f[0]);
                unsigned short h1 = f2bf_rn(u.f[1]);
                unsigned short l0 = f2bf_rn(u.f[0] - bf2f(h0));
                unsigned short l1 = f2bf_rn(u.f[1] - bf2f(h1));
                const int addr = ((b << 10) | (tid << 2)) ^ (b << 4);
                *(unsigned int*)((char*)hs1_hi + addr) =
                    (unsigned int)h0 | ((unsigned int)h1 << 16);
                *(unsigned int*)((char*)hs1_lo + addr) =
                    (unsigned int)l0 | ((unsigned int)l1 << 16);
            }
        }
        __syncthreads();

        // ---- 3 matmuls over this wave's k-half; h0-tile feeds two of them.
        // acc0* -> h0(r) partials; acc1* -> h1(r-1) partials (Wih1 + Whh1).
        f32x4 a0x = {0.f,0.f,0.f,0.f}, a0y = {0.f,0.f,0.f,0.f};
        f32x4 a1x = {0.f,0.f,0.f,0.f}, a1y = {0.f,0.f,0.f,0.f};
#pragma unroll
        for (int ks = 0; ks < 8; ks++) {
            const int kbyte = (khalf << 1) + ks * 64 + klane;
            const int addr  = rbase | (kbyte ^ kxor);
            bf16x8 h0hi = *(const bf16x8*)((const char*)hs0_hi + addr);
            bf16x8 h0lo = *(const bf16x8*)((const char*)hs0_lo + addr);
            bf16x8 h1hi = *(const bf16x8*)((const char*)hs1_hi + addr);
            bf16x8 h1lo = *(const bf16x8*)((const char*)hs1_lo + addr);
            if ((ks & 1) == 0) {
                a0x = __builtin_amdgcn_mfma_f32_16x16x32_bf16(h0hi, w0hi[ks], a0x, 0, 0, 0);
                a0x = __builtin_amdgcn_mfma_f32_16x16x32_bf16(h0hi, w0lo[ks], a0x, 0, 0, 0);
                a0x = __builtin_amdgcn_mfma_f32_16x16x32_bf16(h0lo, w0hi[ks], a0x, 0, 0, 0);
                a1x = __builtin_amdgcn_mfma_f32_16x16x32_bf16(h0hi, wihi[ks], a1x, 0, 0, 0);
                a1x = __builtin_amdgcn_mfma_f32_16x16x32_bf16(h0hi, wilo[ks], a1x, 0, 0, 0);
                a1x = __builtin_amdgcn_mfma_f32_16x16x32_bf16(h0lo, wihi[ks], a1x, 0, 0, 0);
                a1x = __builtin_amdgcn_mfma_f32_16x16x32_bf16(h1hi, w1hi[ks], a1x, 0, 0, 0);
                a1x = __builtin_amdgcn_mfma_f32_16x16x32_bf16(h1hi, w1lo[ks], a1x, 0, 0, 0);
                a1x = __builtin_amdgcn_mfma_f32_16x16x32_bf16(h1lo, w1hi[ks], a1x, 0, 0, 0);
            } else {
                a0y = __builtin_amdgcn_mfma_f32_16x16x32_bf16(h0hi, w0hi[ks], a0y, 0, 0, 0);
                a0y = __builtin_amdgcn_mfma_f32_16x16x32_bf16(h0hi, w0lo[ks], a0y, 0, 0, 0);
                a0y = __builtin_amdgcn_mfma_f32_16x16x32_bf16(h0lo, w0hi[ks], a0y, 0, 0, 0);
                a1y = __builtin_amdgcn_mfma_f32_16x16x32_bf16(h0hi, wihi[ks], a1y, 0, 0, 0);
                a1y = __builtin_amdgcn_mfma_f32_16x16x32_bf16(h0hi, wilo[ks], a1y, 0, 0, 0);
                a1y = __builtin_amdgcn_mfma_f32_16x16x32_bf16(h0lo, wihi[ks], a1y, 0, 0, 0);
                a1y = __builtin_amdgcn_mfma_f32_16x16x32_bf16(h1hi, w1hi[ks], a1y, 0, 0, 0);
                a1y = __builtin_amdgcn_mfma_f32_16x16x32_bf16(h1hi, w1lo[ks], a1y, 0, 0, 0);
                a1y = __builtin_amdgcn_mfma_f32_16x16x32_bf16(h1lo, w1hi[ks], a1y, 0, 0, 0);
            }
        }

        // ---- cross-wave k-half reduce. C/D: col=lane&15, row=(lane>>4)*4+reg;
        // rows 0-7 live in lanes 0-31 (8-15 are discarded duplicates).
        if (lane < 32) {
            const int rrow = (lane >> 4) << 2;
            const int col  = lane & 15;
#pragma unroll
            for (int q = 0; q < 4; q++) {
                red0[wv][rrow + q][col] = a0x[q] + a0y[q];
                red1[wv][rrow + q][col] = a1x[q] + a1y[q];
            }
        }
        __syncthreads();

        // ---- epilogue: 1 slot/thread for each layer; sum the two k-halves
        {
            const int bb = tid >> 5, n2 = tid & 31;
            const int nt2 = (n2 >> 4) << 1;   // {0,1}->red[0]+red[1]; {2,3}
            const int ci  = n2 & 15;
            if (r < T_) {
                float s0 = red0[nt2][bb][ci] + red0[nt2 + 1][bb][ci];
                float h  = fmaxf(s0 + projv, 0.f);
                __hip_atomic_store(p0 + (size_t)r * H_, h,
                                   __ATOMIC_RELAXED, __HIP_MEMORY_SCOPE_AGENT);
            }
            if (r >= 1) {
                float s1 = red1[nt2][bb][ci] + red1[nt2 + 1][bb][ci];
                float h  = fmaxf(s1 + bias1v, 0.f);
                __hip_atomic_store(p1 + (size_t)(r - 1) * H_, h,
                                   __ATOMIC_RELAXED, __HIP_MEMORY_SCOPE_AGENT);
            }
        }

        // ---- team barrier; proj0(r+1) prefetch rides the spin ----
        if (r < T_) {
            __syncthreads();   // drains vmcnt(0): h-stores visible pre-signal
            if (tid == 0)
                __hip_atomic_fetch_add(cnt, 1u,
                                       __ATOMIC_RELAXED, __HIP_MEMORY_SCOPE_AGENT);
            float nextproj = 0.f;
            if (r + 1 < T_)
                nextproj = p0[(size_t)(r + 1) * H_];   // in flight during spin
            if (tid == 0) {
                const unsigned target = (unsigned)TB * (unsigned)(r + 1);
                while (__hip_atomic_load(cnt, __ATOMIC_RELAXED,
                                         __HIP_MEMORY_SCOPE_AGENT) < target) {
                    __builtin_amdgcn_s_sleep(1);
                }
            }
            __syncthreads();   // release block; prefetch drains here too
            projv = nextproj;
        }
    }
}

// ---------------------------------------------------------------------------
// FC head: out[b][c] = sum_i h1[b][i] * Wfc[c][i] + bfc[c]   (unchanged)
// ---------------------------------------------------------------------------
__global__ __launch_bounds__(256) void fc_kernel(
    const float* __restrict__ Hl, const float* __restrict__ Wfc,
    const float* __restrict__ bfc, float* __restrict__ out)
{
    const int b = blockIdx.x;
    const int tid = threadIdx.x;
    const float* hb = Hl + (size_t)b * (T_ * H_);

    float acc[C_];
#pragma unroll
    for (int c = 0; c < C_; c++) acc[c] = 0.f;

    for (int i = tid * 4; i < T_ * H_; i += 256 * 4) {
        float4 hv = *(const float4*)(hb + i);
#pragma unroll
        for (int c = 0; c < C_; c++) {
            float4 wv = *(const float4*)(Wfc + (size_t)c * (T_ * H_) + i);
            acc[c] = fmaf(hv.x, wv.x, fmaf(hv.y, wv.y,
                     fmaf(hv.z, wv.z, fmaf(hv.w, wv.w, acc[c]))));
        }
    }

    __shared__ float red[4][C_];
#pragma unroll
    for (int c = 0; c < C_; c++) {
        float v = acc[c];
#pragma unroll
        for (int off = 32; off >= 1; off >>= 1) v += __shfl_xor(v, off, 64);
        if ((tid & 63) == 0) red[tid >> 6][c] = v;
    }
    __syncthreads();
    if (tid < C_) {
        float v = red[0][tid] + red[1][tid] + red[2][tid] + red[3][tid] + bfc[tid];
        out[(size_t)b * C_ + tid] = v;
    }
}

// ---------------------------------------------------------------------------
// Pipeline (round-13): proj0 GEMM -> FUSED dual-layer scan -> FC.
// The proj1 GEMM is folded into the scan (Wih1 product per round).
// Team counters: 32 teams x 64 B lines in the first 2 KB of d_out (zeroed by
// hipMemsetAsync — graph-safe; fc_kernel fully overwrites d_out at the end).
// Single scan launch -> no gen0 chaining; counter ends at TB*T_ = 2048.
// ---------------------------------------------------------------------------
extern "C" void kernel_launch(void* const* d_in, const int* in_sizes, int n_in,
                              void* d_out, int out_size, void* d_ws, size_t ws_size,
                              hipStream_t stream)
{
    (void)in_sizes; (void)n_in; (void)out_size; (void)ws_size;

    const float* x    = (const float*)d_in[0];
    const float* Wih0 = (const float*)d_in[1];
    const float* Whh0 = (const float*)d_in[2];
    const float* bih0 = (const float*)d_in[3];
    const float* bhh0 = (const float*)d_in[4];
    const float* Wih1 = (const float*)d_in[5];
    const float* Whh1 = (const float*)d_in[6];
    const float* bih1 = (const float*)d_in[7];
    const float* bhh1 = (const float*)d_in[8];
    const float* Wfc  = (const float*)d_in[9];
    const float* bfc  = (const float*)d_in[10];
    float* out = (float*)d_out;

    float* ws0 = (float*)d_ws;                    // [B][T][H] proj0 -> h0
    float* ws1 = ws0 + (size_t)B_ * T_ * H_;      // [B][T][H] h1
    unsigned int* bar = (unsigned int*)d_out;     // TEAMS x 16-dword lines

    hipMemsetAsync(bar, 0, TEAMS * 16 * sizeof(unsigned int), stream);

    dim3 gproj(B_ * T_ / 128, H_ / 128);   // (256, 4)

    gemm_bias_kernel<F_><<<gproj, 256, 0, stream>>>(x, Wih0, bih0, bhh0, ws0);
    fused_scan_kernel<<<TEAMS * TB, 256, 0, stream>>>(
        ws0, ws1, Whh0, Wih1, Whh1, bih1, bhh1, bar);
    fc_kernel<<<B_, 256, 0, stream>>>(ws1, Wfc, bfc, out);
}

// Round 5
// 847.167 us; speedup vs baseline: 2.2379x; 1.2931x over previous
//
#include <hip/hip_runtime.h>
#include <cstddef>

#define B_ 256
#define T_ 128
#define F_ 256
#define H_ 512
#define C_ 10

#define TEAMS 32     // teams; team owns BS batch rows
#define TB    8      // blocks per team (round-14: 8 x 512-thread blocks, 1/CU)
#define BS    8      // batch rows per team
#define NS    64     // n columns per member block

typedef short bf16x8 __attribute__((ext_vector_type(8)));
typedef float f32x4  __attribute__((ext_vector_type(4)));

// round-to-nearest-even fp32 -> bf16
__device__ __forceinline__ unsigned short f2bf_rn(float f) {
    unsigned u = __builtin_bit_cast(unsigned, f);
    u += 0x7fffu + ((u >> 16) & 1u);
    return (unsigned short)(u >> 16);
}
__device__ __forceinline__ float bf2f(unsigned short s) {
    unsigned u = (unsigned)s << 16;
    return __builtin_bit_cast(float, u);
}

// ---------------------------------------------------------------------------
// GEMM: Cout[M, 512] = A[M, K] @ W[512, K]^T + b1 + b2   (fp32, vector ALU)
// BM=BN=128, BK=16, 256 threads, 8x8 micro-tile.  (unchanged, proven)
// Only used for proj0 (x @ W_ih0^T).
// ---------------------------------------------------------------------------
template<int K>
__global__ __launch_bounds__(256, 2) void gemm_bias_kernel(
    const float* __restrict__ A, const float* __restrict__ W,
    const float* __restrict__ b1, const float* __restrict__ b2,
    float* __restrict__ Cout)
{
    __shared__ alignas(16) float As[16][132];
    __shared__ alignas(16) float Ws[16][132];

    const int tid = threadIdx.x;
    const int m0 = blockIdx.x * 128;
    const int n0 = blockIdx.y * 128;
    const int tx = tid & 15;
    const int ty = tid >> 4;

    float acc[8][8];
#pragma unroll
    for (int i = 0; i < 8; i++)
#pragma unroll
        for (int j = 0; j < 8; j++) acc[i][j] = 0.f;

    for (int k0 = 0; k0 < K; k0 += 16) {
#pragma unroll
        for (int i = 0; i < 2; i++) {
            int f = tid + 256 * i;
            int m = f >> 2, k4 = (f & 3) * 4;
            float4 v = *(const float4*)(A + (size_t)(m0 + m) * K + k0 + k4);
            As[k4 + 0][m] = v.x; As[k4 + 1][m] = v.y;
            As[k4 + 2][m] = v.z; As[k4 + 3][m] = v.w;
        }
#pragma unroll
        for (int i = 0; i < 2; i++) {
            int f = tid + 256 * i;
            int n = f >> 2, k4 = (f & 3) * 4;
            float4 v = *(const float4*)(W + (size_t)(n0 + n) * K + k0 + k4);
            Ws[k4 + 0][n] = v.x; Ws[k4 + 1][n] = v.y;
            Ws[k4 + 2][n] = v.z; Ws[k4 + 3][n] = v.w;
        }
        __syncthreads();

#pragma unroll
        for (int kk = 0; kk < 16; kk++) {
            float4 a0 = *(const float4*)&As[kk][ty * 8];
            float4 a1 = *(const float4*)&As[kk][ty * 8 + 4];
            float4 w0 = *(const float4*)&Ws[kk][tx * 8];
            float4 w1 = *(const float4*)&Ws[kk][tx * 8 + 4];
            float a[8] = {a0.x, a0.y, a0.z, a0.w, a1.x, a1.y, a1.z, a1.w};
            float w[8] = {w0.x, w0.y, w0.z, w0.w, w1.x, w1.y, w1.z, w1.w};
#pragma unroll
            for (int i = 0; i < 8; i++)
#pragma unroll
                for (int j = 0; j < 8; j++)
                    acc[i][j] = fmaf(a[i], w[j], acc[i][j]);
        }
        __syncthreads();
    }

    float bias[8];
#pragma unroll
    for (int j = 0; j < 8; j++) {
        int n = n0 + tx * 8 + j;
        bias[j] = b1[n] + b2[n];
    }
#pragma unroll
    for (int i = 0; i < 8; i++) {
        int m = m0 + ty * 8 + i;
        float4 v0 = {acc[i][0] + bias[0], acc[i][1] + bias[1],
                     acc[i][2] + bias[2], acc[i][3] + bias[3]};
        float4 v1 = {acc[i][4] + bias[4], acc[i][5] + bias[5],
                     acc[i][6] + bias[6], acc[i][7] + bias[7]};
        *(float4*)(Cout + (size_t)m * H_ + n0 + tx * 8)     = v0;
        *(float4*)(Cout + (size_t)m * H_ + n0 + tx * 8 + 4) = v1;
    }
}

// ---------------------------------------------------------------------------
// W fragment loader: B-operand [k][n] = W[n][k], split-bf16 hi/lo, 8 ks.
// B-frag layout (16x16x32): col = lane&15, k = khalf + ks*32 + (lane>>4)*8+j.
// Atomic-pinned 8B loads (r7-proven pattern), one-time setup cost.
// ---------------------------------------------------------------------------
__device__ __forceinline__ void load_wfrag(
    const float* __restrict__ W, int wrow, int khalf, int koct,
    bf16x8* bhi, bf16x8* blo)
{
#pragma unroll
    for (int ks = 0; ks < 8; ks++) {
        const float* wp = W + (size_t)wrow * H_ + khalf + ks * 32 + koct;
        const unsigned long long* q = (const unsigned long long*)wp;
        float f[8];
#pragma unroll
        for (int j = 0; j < 4; j++) {
            union { unsigned long long q; float f[2]; } u;
            u.q = __hip_atomic_load(q + j, __ATOMIC_RELAXED,
                                    __HIP_MEMORY_SCOPE_AGENT);
            f[2 * j] = u.f[0]; f[2 * j + 1] = u.f[1];
        }
#pragma unroll
        for (int j = 0; j < 8; j++) {
            unsigned short hi = f2bf_rn(f[j]);
            unsigned short lo = f2bf_rn(f[j] - bf2f(hi));
            bhi[ks][j] = (short)hi;
            blo[ks][j] = (short)lo;
        }
    }
}

// ---------------------------------------------------------------------------
// Round-14: FUSED dual-layer scan, 512-thread blocks, 1 block/CU, TB=8.
//
// r13 analysis: round period = max over members of (chain + work); with
// 2 uncorrelated blocks/CU, random phase overlap ran in-round work at ~2x
// its throughput cost (adding ~1.5k cycles of work cost +6.7k). Fix: 8
// members x 512 threads -> grid 256 = exactly 1 block/CU (r12-proven best
// chain config), all 8 waves phase-locked, no foreign-team contention.
// Weights fit: 384KB/block / 512 thr = 192 VGPR (was impossible at 256 thr).
// Fan-in 8 RMWs/line; per-thread staging halves (8 qwords); 8 waves =
// 4 col-tiles x 2 k-halves, 72 MFMA/wave/round (balanced, same as r13).
//
// Rounds r = 0..T_: round r computes
//   h0(r)   = relu(proj0(r) + Whh0 @ h0(r-1))                    [r < T_]
//   h1(r-1) = relu(Wih1 @ h0(r-1) + b1i+b1h + Whh1 @ h1(r-2))    [r >= 1]
// One team barrier per round (128 barriers total).
//
// Transport/barrier primitives byte-identical to the r5/r7/r9-proven set:
// relaxed agent-scope atomics on ws0/ws1, __syncthreads() drains vmcnt(0)
// before lane 0 signals, monotonic fetch_add counter (flag+ballot banned),
// proj0 prefetch rides the spin. Signal precedes spin -> deadlock-free.
// ---------------------------------------------------------------------------
__global__ __launch_bounds__(512, 2) void fused_scan_kernel(
    float* __restrict__ ws0, float* __restrict__ ws1,
    const float* __restrict__ Whh0, const float* __restrict__ Wih1,
    const float* __restrict__ Whh1,
    const float* __restrict__ bih1, const float* __restrict__ bhh1,
    unsigned int* __restrict__ bar)
{
    __shared__ alignas(16) unsigned short hs0_hi[BS * H_];  // 8 KB
    __shared__ alignas(16) unsigned short hs0_lo[BS * H_];  // 8 KB
    __shared__ alignas(16) unsigned short hs1_hi[BS * H_];  // 8 KB
    __shared__ alignas(16) unsigned short hs1_lo[BS * H_];  // 8 KB
    __shared__ alignas(16) float red0[8][8][17];            // 4.25 KB
    __shared__ alignas(16) float red1[8][8][17];            // 4.25 KB

    const int tid   = threadIdx.x;          // 0..511
    const int team  = blockIdx.x & 31;      // members stride 32 -> same XCD
    const int mem   = blockIdx.x >> 5;      // 0..7
    const int b0    = team * BS;
    const int n0    = mem * NS;
    const int lane  = tid & 63;
    const int wv    = tid >> 6;             // wave 0..7
    const int ct    = wv >> 1;              // col-tile 0..3 (16 cols each)
    const int khalf = (wv & 1) << 8;        // k in [khalf, khalf+256)

    unsigned int* cnt = bar + team * 16;    // 64 B line per team

    // ---- register-stationary weight fragments: 3 matrices, k-half each ----
    const int wrow = n0 + (ct << 4) + (lane & 15);
    const int koct = (lane >> 4) << 3;
    bf16x8 w0hi[8], w0lo[8], wihi[8], wilo[8], w1hi[8], w1lo[8];
    load_wfrag(Whh0, wrow, khalf, koct, w0hi, w0lo);
    load_wfrag(Wih1, wrow, khalf, koct, wihi, wilo);
    load_wfrag(Whh1, wrow, khalf, koct, w1hi, w1lo);

    // ---- per-thread output slot: row = tid>>6 (0..7), col = tid&63 ----
    const int bb = tid >> 6;
    const int cc = tid & 63;
    float* p0 = ws0 + ((size_t)(b0 + bb) * T_) * H_ + n0 + cc;
    float* p1 = ws1 + ((size_t)(b0 + bb) * T_) * H_ + n0 + cc;
    float projv = *p0;                                    // proj0(0) prefetch
    const float bias1v = bih1[n0 + cc] + bhh1[n0 + cc];

    // staging split: qword within row + row-half
    const int qw    = tid & 255;            // 0..255 (256 qwords = 512 elems)
    const int rhalf = (tid >> 8) * 4;       // rows 0-3 or 4-7

    // A-frag read address pieces (row = lane&7; bit3 rows are duplicates)
    const int arow  = lane & 7;
    const int rbase = arow << 10;           // row * 1024 bytes
    const int kxor  = arow << 4;            // swizzle XOR (bits 4-6)
    const int klane = (lane >> 4) << 4;     // k-octet byte offset

    for (int r = 0; r <= T_; r++) {
        // ---- stage h0(r-1) and h1(r-2) as split-bf16 into swizzled LDS ----
        if (r == 0) {
            ((float4*)hs0_hi)[tid] = float4{0.f, 0.f, 0.f, 0.f};
            ((float4*)hs0_lo)[tid] = float4{0.f, 0.f, 0.f, 0.f};
        } else {
            const float* sp = ws0 + ((size_t)b0 * T_ + (r - 1)) * H_;
#pragma unroll
            for (int i = 0; i < 4; i++) {
                const int b = rhalf + i;
                unsigned long long v = __hip_atomic_load(
                    (const unsigned long long*)(sp + (size_t)b * T_ * H_) + qw,
                    __ATOMIC_RELAXED, __HIP_MEMORY_SCOPE_AGENT);
                union { unsigned long long q; float f[2]; } u; u.q = v;
                unsigned short h0 = f2bf_rn(u.f[0]);
                unsigned short h1 = f2bf_rn(u.f[1]);
                unsigned short l0 = f2bf_rn(u.f[0] - bf2f(h0));
                unsigned short l1 = f2bf_rn(u.f[1] - bf2f(h1));
                const int addr = ((b << 10) | (qw << 2)) ^ (b << 4);
                *(unsigned int*)((char*)hs0_hi + addr) =
                    (unsigned int)h0 | ((unsigned int)h1 << 16);
                *(unsigned int*)((char*)hs0_lo + addr) =
                    (unsigned int)l0 | ((unsigned int)l1 << 16);
            }
        }
        if (r <= 1) {
            ((float4*)hs1_hi)[tid] = float4{0.f, 0.f, 0.f, 0.f};
            ((float4*)hs1_lo)[tid] = float4{0.f, 0.f, 0.f, 0.f};
        } else {
            const float* sp = ws1 + ((size_t)b0 * T_ + (r - 2)) * H_;
#pragma unroll
            for (int i = 0; i < 4; i++) {
                const int b = rhalf + i;
                unsigned long long v = __hip_atomic_load(
                    (const unsigned long long*)(sp + (size_t)b * T_ * H_) + qw,
                    __ATOMIC_RELAXED, __HIP_MEMORY_SCOPE_AGENT);
                union { unsigned long long q; float f[2]; } u; u.q = v;
                unsigned short h0 = f2bf_rn(u.f[0]);
                unsigned short h1 = f2bf_rn(u.f[1]);
                unsigned short l0 = f2bf_rn(u.f[0] - bf2f(h0));
                unsigned short l1 = f2bf_rn(u.f[1] - bf2f(h1));
                const int addr = ((b << 10) | (qw << 2)) ^ (b << 4);
                *(unsigned int*)((char*)hs1_hi + addr) =
                    (unsigned int)h0 | ((unsigned int)h1 << 16);
                *(unsigned int*)((char*)hs1_lo + addr) =
                    (unsigned int)l0 | ((unsigned int)l1 << 16);
            }
        }
        __syncthreads();

        // ---- 3 matmuls over this wave's (col-tile, k-half) slot ----
        f32x4 a0x = {0.f,0.f,0.f,0.f}, a0y = {0.f,0.f,0.f,0.f};
        f32x4 a1x = {0.f,0.f,0.f,0.f}, a1y = {0.f,0.f,0.f,0.f};
#pragma unroll
        for (int ks = 0; ks < 8; ks++) {
            const int kbyte = (khalf << 1) + ks * 64 + klane;
            const int addr  = rbase | (kbyte ^ kxor);
            bf16x8 h0hi = *(const bf16x8*)((const char*)hs0_hi + addr);
            bf16x8 h0lo = *(const bf16x8*)((const char*)hs0_lo + addr);
            bf16x8 h1hi = *(const bf16x8*)((const char*)hs1_hi + addr);
            bf16x8 h1lo = *(const bf16x8*)((const char*)hs1_lo + addr);
            if ((ks & 1) == 0) {
                a0x = __builtin_amdgcn_mfma_f32_16x16x32_bf16(h0hi, w0hi[ks], a0x, 0, 0, 0);
                a0x = __builtin_amdgcn_mfma_f32_16x16x32_bf16(h0hi, w0lo[ks], a0x, 0, 0, 0);
                a0x = __builtin_amdgcn_mfma_f32_16x16x32_bf16(h0lo, w0hi[ks], a0x, 0, 0, 0);
                a1x = __builtin_amdgcn_mfma_f32_16x16x32_bf16(h0hi, wihi[ks], a1x, 0, 0, 0);
                a1x = __builtin_amdgcn_mfma_f32_16x16x32_bf16(h0hi, wilo[ks], a1x, 0, 0, 0);
                a1x = __builtin_amdgcn_mfma_f32_16x16x32_bf16(h0lo, wihi[ks], a1x, 0, 0, 0);
                a1x = __builtin_amdgcn_mfma_f32_16x16x32_bf16(h1hi, w1hi[ks], a1x, 0, 0, 0);
                a1x = __builtin_amdgcn_mfma_f32_16x16x32_bf16(h1hi, w1lo[ks], a1x, 0, 0, 0);
                a1x = __builtin_amdgcn_mfma_f32_16x16x32_bf16(h1lo, w1hi[ks], a1x, 0, 0, 0);
            } else {
                a0y = __builtin_amdgcn_mfma_f32_16x16x32_bf16(h0hi, w0hi[ks], a0y, 0, 0, 0);
                a0y = __builtin_amdgcn_mfma_f32_16x16x32_bf16(h0hi, w0lo[ks], a0y, 0, 0, 0);
                a0y = __builtin_amdgcn_mfma_f32_16x16x32_bf16(h0lo, w0hi[ks], a0y, 0, 0, 0);
                a1y = __builtin_amdgcn_mfma_f32_16x16x32_bf16(h0hi, wihi[ks], a1y, 0, 0, 0);
                a1y = __builtin_amdgcn_mfma_f32_16x16x32_bf16(h0hi, wilo[ks], a1y, 0, 0, 0);
                a1y = __builtin_amdgcn_mfma_f32_16x16x32_bf16(h0lo, wihi[ks], a1y, 0, 0, 0);
                a1y = __builtin_amdgcn_mfma_f32_16x16x32_bf16(h1hi, w1hi[ks], a1y, 0, 0, 0);
                a1y = __builtin_amdgcn_mfma_f32_16x16x32_bf16(h1hi, w1lo[ks], a1y, 0, 0, 0);
                a1y = __builtin_amdgcn_mfma_f32_16x16x32_bf16(h1lo, w1hi[ks], a1y, 0, 0, 0);
            }
        }

        // ---- per-wave k-half partials -> LDS. C/D: col=lane&15,
        // row=(lane>>4)*4+reg; rows 0-7 live in lanes 0-31.
        if (lane < 32) {
            const int rrow = (lane >> 4) << 2;
            const int col  = lane & 15;
#pragma unroll
            for (int q = 0; q < 4; q++) {
                red0[wv][rrow + q][col] = a0x[q] + a0y[q];
                red1[wv][rrow + q][col] = a1x[q] + a1y[q];
            }
        }
        __syncthreads();

        // ---- epilogue: 1 slot/thread/layer; sum the two k-halves ----
        {
            const int wv0 = (cc >> 4) << 1;   // waves ct*2, ct*2+1
            const int ci  = cc & 15;
            if (r < T_) {
                float s0 = red0[wv0][bb][ci] + red0[wv0 + 1][bb][ci];
                float h  = fmaxf(s0 + projv, 0.f);
                __hip_atomic_store(p0 + (size_t)r * H_, h,
                                   __ATOMIC_RELAXED, __HIP_MEMORY_SCOPE_AGENT);
            }
            if (r >= 1) {
                float s1 = red1[wv0][bb][ci] + red1[wv0 + 1][bb][ci];
                float h  = fmaxf(s1 + bias1v, 0.f);
                __hip_atomic_store(p1 + (size_t)(r - 1) * H_, h,
                                   __ATOMIC_RELAXED, __HIP_MEMORY_SCOPE_AGENT);
            }
        }

        // ---- team barrier; proj0(r+1) prefetch rides the spin ----
        if (r < T_) {
            __syncthreads();   // drains vmcnt(0): h-stores visible pre-signal
            if (tid == 0)
                __hip_atomic_fetch_add(cnt, 1u,
                                       __ATOMIC_RELAXED, __HIP_MEMORY_SCOPE_AGENT);
            float nextproj = 0.f;
            if (r + 1 < T_)
                nextproj = p0[(size_t)(r + 1) * H_];   // in flight during spin
            if (tid == 0) {
                const unsigned target = (unsigned)TB * (unsigned)(r + 1);
                while (__hip_atomic_load(cnt, __ATOMIC_RELAXED,
                                         __HIP_MEMORY_SCOPE_AGENT) < target) {
                    __builtin_amdgcn_s_sleep(1);
                }
            }
            __syncthreads();   // release block; prefetch drains here too
            projv = nextproj;
        }
    }
}

// ---------------------------------------------------------------------------
// FC head: out[b][c] = sum_i h1[b][i] * Wfc[c][i] + bfc[c]   (unchanged)
// ---------------------------------------------------------------------------
__global__ __launch_bounds__(256) void fc_kernel(
    const float* __restrict__ Hl, const float* __restrict__ Wfc,
    const float* __restrict__ bfc, float* __restrict__ out)
{
    const int b = blockIdx.x;
    const int tid = threadIdx.x;
    const float* hb = Hl + (size_t)b * (T_ * H_);

    float acc[C_];
#pragma unroll
    for (int c = 0; c < C_; c++) acc[c] = 0.f;

    for (int i = tid * 4; i < T_ * H_; i += 256 * 4) {
        float4 hv = *(const float4*)(hb + i);
#pragma unroll
        for (int c = 0; c < C_; c++) {
            float4 wv = *(const float4*)(Wfc + (size_t)c * (T_ * H_) + i);
            acc[c] = fmaf(hv.x, wv.x, fmaf(hv.y, wv.y,
                     fmaf(hv.z, wv.z, fmaf(hv.w, wv.w, acc[c]))));
        }
    }

    __shared__ float red[4][C_];
#pragma unroll
    for (int c = 0; c < C_; c++) {
        float v = acc[c];
#pragma unroll
        for (int off = 32; off >= 1; off >>= 1) v += __shfl_xor(v, off, 64);
        if ((tid & 63) == 0) red[tid >> 6][c] = v;
    }
    __syncthreads();
    if (tid < C_) {
        float v = red[0][tid] + red[1][tid] + red[2][tid] + red[3][tid] + bfc[tid];
        out[(size_t)b * C_ + tid] = v;
    }
}

// ---------------------------------------------------------------------------
// Pipeline (round-14): proj0 GEMM -> FUSED dual-layer scan (512-thr) -> FC.
// Team counters: 32 teams x 64 B lines in the first 2 KB of d_out (zeroed by
// hipMemsetAsync — graph-safe; fc_kernel fully overwrites d_out at the end).
// Counter ends at TB*T_ = 1024 per team.
// ---------------------------------------------------------------------------
extern "C" void kernel_launch(void* const* d_in, const int* in_sizes, int n_in,
                              void* d_out, int out_size, void* d_ws, size_t ws_size,
                              hipStream_t stream)
{
    (void)in_sizes; (void)n_in; (void)out_size; (void)ws_size;

    const float* x    = (const float*)d_in[0];
    const float* Wih0 = (const float*)d_in[1];
    const float* Whh0 = (const float*)d_in[2];
    const float* bih0 = (const float*)d_in[3];
    const float* bhh0 = (const float*)d_in[4];
    const float* Wih1 = (const float*)d_in[5];
    const float* Whh1 = (const float*)d_in[6];
    const float* bih1 = (const float*)d_in[7];
    const float* bhh1 = (const float*)d_in[8];
    const float* Wfc  = (const float*)d_in[9];
    const float* bfc  = (const float*)d_in[10];
    float* out = (float*)d_out;

    float* ws0 = (float*)d_ws;                    // [B][T][H] proj0 -> h0
    float* ws1 = ws0 + (size_t)B_ * T_ * H_;      // [B][T][H] h1
    unsigned int* bar = (unsigned int*)d_out;     // TEAMS x 16-dword lines

    hipMemsetAsync(bar, 0, TEAMS * 16 * sizeof(unsigned int), stream);

    dim3 gproj(B_ * T_ / 128, H_ / 128);   // (256, 4)

    gemm_bias_kernel<F_><<<gproj, 256, 0, stream>>>(x, Wih0, bih0, bhh0, ws0);
    fused_scan_kernel<<<TEAMS * TB, 512, 0, stream>>>(
        ws0, ws1, Whh0, Wih1, Whh1, bih1, bhh1, bar);
    fc_kernel<<<B_, 256, 0, stream>>>(ws1, Wfc, bfc, out);
}